// Round 1
// baseline (383.531 us; speedup 1.0000x reference)
//
#include <hip/hip_runtime.h>
#include <cstdint>
#include <cstddef>

#define NB 16
#define NC 128
#define NH 128
#define NW 128
#define HM 1024
#define WM 1024
#define HW (NH*NW)
#define NHEADS 4
#define HDIM 32
// SIGMA2 = 2*0.3^2 = 0.18
#define INV_SIGMA2 5.555555555555555f

// ---- workspace layout (floats) ----
#define WS_M     0          // [B*2][128][128] downsampled masks (raw values)
#define WS_PART  524288     // [B*2][8][4] partial stats (msum, cnt, cy, cx)
#define WS_NUM   525312     // [B*2][128] pooled numerators
#define WS_NODES 529408     // [B*2][128] final node features
#define WS_WXY   533504     // [B*2][2][128] gaussian factors: [..][0][w]=wx, [..][1][h]=wy

// ============ Kernel A: downsample masks + partial stats ============
// grid = B*2*8 (16 rows per block), block = 256
__global__ void kA(const float* __restrict__ masks, float* __restrict__ ws) {
    float* m_ds = ws + WS_M;
    float* part = ws + WS_PART;
    int blk = blockIdx.x;
    int b2 = blk >> 3;          // b*2 + n
    int chunk = blk & 7;
    int tid = threadIdx.x;
    int wcol = tid & 127;
    int rofs = tid >> 7;        // 0 or 1
    const float* mp = masks + (size_t)b2 * (HM * WM);
    float msum = 0.f, cnt = 0.f, cy = 0.f, cx = 0.f;
#pragma unroll
    for (int it = 0; it < 8; ++it) {
        int r = chunk * 16 + it * 2 + rofs;
        float v = mp[(size_t)(r * 8) * WM + wcol * 8];   // nearest: iy=h*8, ix=w*8
        m_ds[(size_t)b2 * HW + r * 128 + wcol] = v;
        msum += v;
        if (v > 0.5f) { cnt += 1.0f; cy += (float)r; cx += (float)wcol; }
    }
    __shared__ float r0[256], r1[256], r2[256], r3[256];
    r0[tid] = msum; r1[tid] = cnt; r2[tid] = cy; r3[tid] = cx;
    __syncthreads();
    for (int s = 128; s > 0; s >>= 1) {
        if (tid < s) { r0[tid] += r0[tid+s]; r1[tid] += r1[tid+s];
                       r2[tid] += r2[tid+s]; r3[tid] += r3[tid+s]; }
        __syncthreads();
    }
    if (tid == 0) {
        float* p = part + (b2 * 8 + chunk) * 4;
        p[0] = r0[0]; p[1] = r1[0]; p[2] = r2[0]; p[3] = r3[0];
    }
}

// ============ Kernel B: node pooling ============
// grid = B*C = 2048, block = 256
__global__ void kB(const float* __restrict__ x, const float* __restrict__ ws_full) {
    const float* ws_m = ws_full + WS_M;
    float* num = (float*)(ws_full + WS_NUM);
    int b = blockIdx.x >> 7, c = blockIdx.x & 127;
    int tid = threadIdx.x;
    const float4* xp = (const float4*)(x + ((size_t)b * NC + c) * HW);
    const float4* m0 = (const float4*)(ws_m + (size_t)(b * 2 + 0) * HW);
    const float4* m1 = (const float4*)(ws_m + (size_t)(b * 2 + 1) * HW);
    float a0 = 0.f, a1 = 0.f;
#pragma unroll
    for (int i = 0; i < 16; ++i) {
        int idx = i * 256 + tid;
        float4 xv = xp[idx];
        float4 v0 = m0[idx];
        float4 v1 = m1[idx];
        a0 += xv.x*v0.x + xv.y*v0.y + xv.z*v0.z + xv.w*v0.w;
        a1 += xv.x*v1.x + xv.y*v1.y + xv.z*v1.z + xv.w*v1.w;
    }
    __shared__ float r0[256], r1[256];
    r0[tid] = a0; r1[tid] = a1;
    __syncthreads();
    for (int s = 128; s > 0; s >>= 1) {
        if (tid < s) { r0[tid] += r0[tid+s]; r1[tid] += r1[tid+s]; }
        __syncthreads();
    }
    if (tid == 0) {
        num[(b * 2 + 0) * 128 + c] = r0[0];
        num[(b * 2 + 1) * 128 + c] = r1[0];
    }
}

// ============ Kernel C: tiny graph attention + FFN + gaussian factors ============
// grid = B = 16, block = 256 (tid = i*128 + c ; i = node 0/1, c = channel)
__device__ __forceinline__ float rowReduce(float v, float* red, int tid) {
    red[tid] = v;
    __syncthreads();
    int base = tid & 128;   // 0 or 128 -> independent reduce per node-row
    int lane = tid & 127;
    for (int s = 64; s > 0; s >>= 1) {
        if (lane < s) red[tid] += red[tid + s];
        __syncthreads();
    }
    float r = red[base];
    __syncthreads();
    return r;
}

__global__ void kC(const float* __restrict__ Wq, const float* __restrict__ bq,
                   const float* __restrict__ Wk, const float* __restrict__ bk,
                   const float* __restrict__ Wv, const float* __restrict__ bv,
                   const float* __restrict__ Wo, const float* __restrict__ bo,
                   const float* __restrict__ ln1w, const float* __restrict__ ln1b,
                   const float* __restrict__ W1, const float* __restrict__ b1,
                   const float* __restrict__ W2, const float* __restrict__ b2,
                   const float* __restrict__ ln2w, const float* __restrict__ ln2b,
                   float* __restrict__ ws) {
    int b = blockIdx.x;
    int tid = threadIdx.x;
    int c = tid & 127;
    int i = tid >> 7;   // node index

    const float* part = ws + WS_PART;
    const float* num  = ws + WS_NUM;
    float* nodesf = ws + WS_NODES;
    float* wxy    = ws + WS_WXY;

    __shared__ float s_n0[2][128], sQ[2][128], sK[2][128], sV[2][128];
    __shared__ float s_o[2][128], s_n1[2][128];
    __shared__ float s_hid[2][256];
    __shared__ float red[256];
    __shared__ float s_sc[16];
    __shared__ float s_at[NHEADS][2][2];
    __shared__ float s_px[2], s_py[2], s_den[2];

    if (tid < 2) {
        int n = tid;
        float msum = 0.f, cnt = 0.f, cy = 0.f, cx = 0.f;
        const float* p = part + ((b * 2 + n) * 8) * 4;
        for (int ch = 0; ch < 8; ++ch) {
            msum += p[ch*4+0]; cnt += p[ch*4+1]; cy += p[ch*4+2]; cx += p[ch*4+3];
        }
        s_den[n] = msum + 1e-6f;
        float cm = fmaxf(cnt, 1.0f);
        float cyv = cy / cm, cxv = cx / cm;
        s_px[n] = cxv / 64.0f - 1.0f;   // cx/W*2 - 1
        s_py[n] = cyv / 64.0f - 1.0f;
    }
    __syncthreads();

    s_n0[i][c] = num[(b * 2 + i) * 128 + c] / s_den[i];
    __syncthreads();

    // Q/K/V projections: out[c] = sum_k n0[k] * W[c][k] + b[c]
    {
        float aq = bq[c], ak = bk[c], av = bv[c];
        const float* wq = Wq + c * 128;
        const float* wk = Wk + c * 128;
        const float* wv = Wv + c * 128;
        for (int k = 0; k < 128; ++k) {
            float nv = s_n0[i][k];
            aq += nv * wq[k]; ak += nv * wk[k]; av += nv * wv[k];
        }
        sQ[i][c] = aq; sK[i][c] = ak; sV[i][c] = av;
    }
    __syncthreads();

    // scores per (head, i, j)
    if (tid < 16) {
        int h = tid >> 2, ii = (tid >> 1) & 1, j = tid & 1;
        float s = 0.f;
        for (int d = 0; d < HDIM; ++d) s += sQ[ii][h*HDIM+d] * sK[j][h*HDIM+d];
        s *= 0.17677669529663687f;  // 1/sqrt(32)
        if (ii != j) {
            float dx = s_px[0] - s_px[1], dy = s_py[0] - s_py[1];
            float d2 = dx*dx + dy*dy;
            if (d2 > 0.f) s -= sqrtf(d2);
        }
        s_sc[tid] = s;
    }
    __syncthreads();

    if (tid < 8) {
        int h = tid >> 1, ii = tid & 1;
        float s0 = s_sc[h*4 + ii*2 + 0], s1 = s_sc[h*4 + ii*2 + 1];
        float mx = fmaxf(s0, s1);
        float e0 = expf(s0 - mx), e1 = expf(s1 - mx);
        float inv = 1.0f / (e0 + e1);
        s_at[h][ii][0] = e0 * inv;
        s_at[h][ii][1] = e1 * inv;
    }
    __syncthreads();

    {
        int h = c >> 5;
        s_o[i][c] = s_at[h][i][0] * sV[0][c] + s_at[h][i][1] * sV[1][c];
    }
    __syncthreads();

    float h1;
    {
        float acc = bo[c];
        const float* wo = Wo + c * 128;
        for (int k = 0; k < 128; ++k) acc += s_o[i][k] * wo[k];
        h1 = s_n0[i][c] + acc;
    }
    // LN1
    {
        float mean = rowReduce(h1, red, tid) * (1.0f / 128.0f);
        float d = h1 - mean;
        float var = rowReduce(d * d, red, tid) * (1.0f / 128.0f);
        float nrm = d * rsqrtf(var + 1e-5f);
        s_n1[i][c] = nrm * ln1w[c] + ln1b[c];
    }
    __syncthreads();

    // FFN hidden (256), each thread does j = c and c+128 for its node
    for (int half = 0; half < 2; ++half) {
        int j = c + half * 128;
        float acc = b1[j];
        const float* w1 = W1 + j * 128;
        for (int k = 0; k < 128; ++k) acc += s_n1[i][k] * w1[k];
        s_hid[i][j] = fmaxf(acc, 0.0f);
    }
    __syncthreads();

    float h2;
    {
        float acc = b2[c];
        const float* w2 = W2 + c * 256;
        for (int j = 0; j < 256; ++j) acc += s_hid[i][j] * w2[j];
        h2 = s_n1[i][c] + acc;
    }
    // LN2 -> final nodes
    {
        float mean = rowReduce(h2, red, tid) * (1.0f / 128.0f);
        float d = h2 - mean;
        float var = rowReduce(d * d, red, tid) * (1.0f / 128.0f);
        float nrm = d * rsqrtf(var + 1e-5f);
        nodesf[(b * 2 + i) * 128 + c] = nrm * ln2w[c] + ln2b[c];
    }
    // separable gaussian factors (linspace(-1,1,128))
    {
        float g = (float)c * (2.0f / 127.0f) - 1.0f;
        float dx = g - s_px[i];
        float dy = g - s_py[i];
        wxy[((b*2+i)*2 + 0) * 128 + c] = expf(-dx * dx * INV_SIGMA2);
        wxy[((b*2+i)*2 + 1) * 128 + c] = expf(-dy * dy * INV_SIGMA2);
    }
}

// ============ Kernel D: gaussian broadcast + residual ============
// grid = B*C = 2048, block = 256
__global__ void kD(const float* __restrict__ x, const float* __restrict__ ws,
                   float* __restrict__ out) {
    const float* nodesf = ws + WS_NODES;
    const float* wxy    = ws + WS_WXY;
    int b = blockIdx.x >> 7, c = blockIdx.x & 127;
    int tid = threadIdx.x;
    __shared__ float4 swx0[32], swx1[32];
    __shared__ float swy0[128], swy1[128];
    if (tid < 128) {
        swy0[tid] = wxy[((b*2+0)*2 + 1) * 128 + tid];
        swy1[tid] = wxy[((b*2+1)*2 + 1) * 128 + tid];
    } else {
        int t = tid - 128;
        if (t < 32)      swx0[t]      = ((const float4*)(wxy + ((b*2+0)*2 + 0) * 128))[t];
        else if (t < 64) swx1[t - 32] = ((const float4*)(wxy + ((b*2+1)*2 + 0) * 128))[t - 32];
    }
    float n0 = nodesf[(b * 2 + 0) * 128 + c];
    float n1 = nodesf[(b * 2 + 1) * 128 + c];
    __syncthreads();
    const float4* xp = (const float4*)(x   + ((size_t)b * NC + c) * HW);
    float4*       op = (float4*)      (out + ((size_t)b * NC + c) * HW);
#pragma unroll
    for (int it = 0; it < 16; ++it) {
        int p4 = it * 256 + tid;
        int h = p4 >> 5;       // 32 float4 per row
        int w4 = p4 & 31;
        float a0 = n0 * swy0[h];
        float a1 = n1 * swy1[h];
        float4 xv = xp[p4];
        float4 wx0 = swx0[w4], wx1 = swx1[w4];
        float4 r;
        r.x = xv.x + a0 * wx0.x + a1 * wx1.x;
        r.y = xv.y + a0 * wx0.y + a1 * wx1.y;
        r.z = xv.z + a0 * wx0.z + a1 * wx1.z;
        r.w = xv.w + a0 * wx0.w + a1 * wx1.w;
        op[p4] = r;
    }
}

extern "C" void kernel_launch(void* const* d_in, const int* in_sizes, int n_in,
                              void* d_out, int out_size, void* d_ws, size_t ws_size,
                              hipStream_t stream) {
    const float* x     = (const float*)d_in[0];
    const float* masks = (const float*)d_in[1];
    const float* Wq    = (const float*)d_in[2];
    const float* bq    = (const float*)d_in[3];
    const float* Wk    = (const float*)d_in[4];
    const float* bk    = (const float*)d_in[5];
    const float* Wv    = (const float*)d_in[6];
    const float* bv    = (const float*)d_in[7];
    const float* Wo    = (const float*)d_in[8];
    const float* bo    = (const float*)d_in[9];
    const float* ln1w  = (const float*)d_in[10];
    const float* ln1b  = (const float*)d_in[11];
    const float* W1    = (const float*)d_in[12];
    const float* b1    = (const float*)d_in[13];
    const float* W2    = (const float*)d_in[14];
    const float* b2    = (const float*)d_in[15];
    const float* ln2w  = (const float*)d_in[16];
    const float* ln2b  = (const float*)d_in[17];
    float* out = (float*)d_out;
    float* ws  = (float*)d_ws;

    hipLaunchKernelGGL(kA, dim3(NB * 2 * 8), dim3(256), 0, stream, masks, ws);
    hipLaunchKernelGGL(kB, dim3(NB * NC), dim3(256), 0, stream, x, ws);
    hipLaunchKernelGGL(kC, dim3(NB), dim3(256), 0, stream,
                       Wq, bq, Wk, bk, Wv, bv, Wo, bo, ln1w, ln1b,
                       W1, b1, W2, b2, ln2w, ln2b, ws);
    hipLaunchKernelGGL(kD, dim3(NB * NC), dim3(256), 0, stream, x, ws, out);
}